// Round 4
// baseline (295.979 us; speedup 1.0000x reference)
//
#include <hip/hip_runtime.h>
#include <math.h>

#define BB 2
#define NN 2048
#define KK 30
#define NRBF 16
#define V_DIM 213
#define E_DIM 480
#define NODES (BB*NN)

typedef unsigned long long u64;
typedef unsigned int u32;
typedef float v4f __attribute__((ext_vector_type(4)));

// ---------- small helpers ----------
__device__ __forceinline__ float sgnf(float x){ return (x>0.f)?1.f:((x<0.f)?-1.f:0.f); }

__device__ __forceinline__ void cross3(const float* a, const float* b, float* c){
  c[0]=a[1]*b[2]-a[2]*b[1];
  c[1]=a[2]*b[0]-a[0]*b[2];
  c[2]=a[0]*b[1]-a[1]*b[0];
}
__device__ __forceinline__ void norm3e(float* v){ // v / max(||v||, 1e-8)
  float n = sqrtf(v[0]*v[0]+v[1]*v[1]+v[2]*v[2]);
  float inv = 1.0f/fmaxf(n,1e-8f);
  v[0]*=inv; v[1]*=inv; v[2]*=inv;
}
__device__ __forceinline__ float dot3(const float* a, const float* b){
  return a[0]*b[0]+a[1]*b[1]+a[2]*b[2];
}

// Given atoms p[12]=N,Ca,C,O of a residue, produce full[30]:
// [0..11]=N,Ca,C,O  [12..14]=Cb  [15..17]=V0  [18..20]=V1  [21..29]=Q rows (b1,n0,b1xn0)
__device__ __forceinline__ void node_derived(const float* p, const float (*va)[3],
                                             float* full, int isLast){
  for(int i=0;i<12;i++) full[i]=p[i];
  float bv[3],cv[3],av[3];
  for(int c=0;c<3;c++){ bv[c]=p[3+c]-p[c]; cv[c]=p[6+c]-p[3+c]; }
  cross3(bv,cv,av);
  for(int c=0;c<3;c++)
    full[12+c] = -0.58273431f*av[c] + 0.56802827f*bv[c] - 0.54067466f*cv[c] + p[3+c];
  for(int i=0;i<2;i++)
    for(int c=0;c<3;c++)
      full[15+3*i+c] = va[i][0]*av[c] + va[i][1]*bv[c] + va[i][2]*cv[c] + p[3+c];
  if (isLast){
    for(int i=0;i<9;i++) full[21+i]=0.f;   // padded Q row for last node
  } else {
    float u0[3],u1[3];
    for(int c=0;c<3;c++){ u0[c]=bv[c]; u1[c]=cv[c]; }
    norm3e(u0); norm3e(u1);
    float n0[3]; cross3(u0,u1,n0); norm3e(n0);
    float b1[3]; for(int c=0;c<3;c++) b1[c]=u0[c]-u1[c];
    norm3e(b1);
    float c2[3]; cross3(b1,n0,c2);
    for(int c=0;c<3;c++){ full[21+c]=b1[c]; full[24+c]=n0[c]; full[27+c]=c2[c]; }
  }
}

// atom indices: N=0,Ca=1,C=2,O=3,Cb=4,V0=5,V1=6
__device__ __constant__ int c_epA[29] = {1,1,2,1,0,4,1,4,0,4,3,4,2,4,1,3,2,2,0,2,3,0,0,3,3, 5,6,6,5};
__device__ __constant__ int c_epB[29] = {1,2,1,0,1,1,4,0,4,3,4,2,4,4,3,1,2,0,2,3,2,0,3,0,3, 5,6,5,6};
__device__ __constant__ int c_npA[12] = {1,1,1,0,0,3,1,4,4,2,6,5};
__device__ __constant__ int c_npB[12] = {0,2,3,2,3,2,4,0,3,4,5,6};

#define NBIN 2048
#define BINSHIFT 21   // bin = float_bits >> 21 (sign0 + exp8 + mant2)

// ---------- fused dispatch 1: topk (blocks < NODES) + node prep (last 16 blocks) ----------
__global__ __launch_bounds__(256) void topk_prep_kernel(const float* __restrict__ X,
                                                        const float* __restrict__ mask,
                                                        const float* __restrict__ vatoms,
                                                        float* __restrict__ outIdx,
                                                        float* __restrict__ outV,
                                                        float* __restrict__ packets){
  const int t = threadIdx.x;

  if (blockIdx.x < NODES){
    // ================= top-k via histogram prune + rank sort =================
    // bins stored transposed: logical bin b at LDS index (b&7)*256 + (b>>3)
    __shared__ u32 bins[NBIN];
    __shared__ u64 cand[NN];
    __shared__ float wred[4];
    __shared__ u32 wsum[4];
    __shared__ int s_cutbin;
    __shared__ u32 s_m;

    const int row = blockIdx.x;
    const int b = row / NN, n = row % NN;
    const int w = t>>6, l = t&63;

    for (int i=t;i<NBIN;i+=256) bins[i]=0;
    if (t==0) s_m=0;

    const float* Xb = X + (size_t)b*NN*12;
    const float* mb = mask + (size_t)b*NN;
    const float cx=Xb[n*12+3], cy=Xb[n*12+4], cz=Xb[n*12+5], mn=mb[n];

    // distances, bit-exact IEEE (same op order as passing rounds 1-2)
    float dval[8];
    float lmax = -1e30f;
    #pragma unroll
    for (int s=0;s<8;s++){
      int i = s*256+t;
      const float* p = Xb + i*12;
      float dx=__fsub_rn(p[3],cx), dy=__fsub_rn(p[4],cy), dz=__fsub_rn(p[5],cz);
      float ss=__fadd_rn(__fadd_rn(__fadd_rn(__fmul_rn(dx,dx),__fmul_rn(dy,dy)),
                                   __fmul_rn(dz,dz)), 1e-6f);
      float d = __fsqrt_rn(ss);
      float m2 = __fmul_rn(mb[i], mn);
      float om = __fsub_rn(1.0f, m2);
      float D  = __fadd_rn(__fmul_rn(om,10000.0f), __fmul_rn(m2,d));
      dval[s]=D;
      lmax = fmaxf(lmax, D);
    }
    #pragma unroll
    for (int off=32; off; off>>=1) lmax = fmaxf(lmax, __shfl_xor(lmax, off));
    if (l==0) wred[w]=lmax;
    __syncthreads();                       // bins zeroed, wred ready
    const float srmax = fmaxf(fmaxf(wred[0],wred[1]), fmaxf(wred[2],wred[3]));
    const float radd = __fadd_rn(srmax, 1.0f);

    u32 keyb[8];
    #pragma unroll
    for (int s=0;s<8;s++){
      int i = s*256+t;
      float m2 = __fmul_rn(mb[i], mn);
      float om = __fsub_rn(1.0f, m2);
      float Dj = __fadd_rn(dval[s], __fmul_rn(om, radd));
      u32 kb = __float_as_uint(Dj);        // Dj >= 0 -> bits order-isomorphic
      keyb[s]=kb;
      u32 bin = kb >> BINSHIFT;
      atomicAdd(&bins[(bin&7)*256 + (bin>>3)], 1u);
    }
    __syncthreads();

    // scan: thread t owns logical bins [8t, 8t+8)
    u32 g8[8]; u32 lsum=0;
    #pragma unroll
    for (int j=0;j<8;j++){ g8[j]=bins[j*256+t]; lsum+=g8[j]; }
    u32 inc=lsum;
    #pragma unroll
    for (int off=1; off<64; off<<=1){
      u32 o = __shfl_up(inc, off);
      if (l >= off) inc += o;
    }
    if (l==63) wsum[w]=inc;
    __syncthreads();
    u32 waveoff=0;
    for (int ww=0; ww<w; ww++) waveoff += wsum[ww];
    u32 run = waveoff + inc - lsum;        // exclusive prefix of this 8-bin group
    #pragma unroll
    for (int j=0;j<8;j++){
      u32 c=g8[j];
      if (run < KK && run + c >= KK) s_cutbin = 8*t+j;   // unique writer
      run += c;
    }
    __syncthreads();
    const int cutbin = s_cutbin;

    // collect candidates (all bins <= cutbin); >=30 guaranteed
    #pragma unroll
    for (int s=0;s<8;s++){
      if ((int)(keyb[s] >> BINSHIFT) <= cutbin){
        u32 slot = atomicAdd(&s_m, 1u);
        cand[slot] = ((u64)keyb[s] << 32) | (u32)(s*256+t);
      }
    }
    __syncthreads();
    const int m = (int)s_m;

    // exact rank (keys unique: idx in low bits) -> scatter; order == lax.top_k
    for (int cix=t; cix<m; cix+=256){
      u64 mykey = cand[cix];
      int rank=0;
      for (int j=0;j<m;j++) rank += (cand[j] < mykey) ? 1 : 0;
      if (rank < KK)
        outIdx[(size_t)row*KK + rank] = (float)(u32)(mykey & 0xffffffffu);
    }
    return;
  }

  // ================= prep blocks: V features + derived packets =================
  const int node = (blockIdx.x - NODES)*256 + t;
  if (node >= NODES) return;
  const int b = node/NN, n = node%NN;

  float va[2][3];
  for(int i=0;i<2;i++){
    float x=vatoms[3*i],y=vatoms[3*i+1],z=vatoms[3*i+2];
    float inv=1.f/sqrtf(x*x+y*y+z*z);
    va[i][0]=x*inv; va[i][1]=y*inv; va[i][2]=z*inv;
  }
  float p[12];
  { const float* q = X + (size_t)node*12; for(int i=0;i<12;i++) p[i]=q[i]; }
  float full[30];
  node_derived(p, va, full, n==NN-1);

  {
    float* pk = packets + (size_t)node*32;
    for (int i=0;i<30;i++) pk[i]=full[i];
    pk[30]=0.f; pk[31]=0.f;
  }

  float* vout = outV + (size_t)node*V_DIM;

  for (int blk=0; blk<12; blk++){
    const float* a=&full[3*c_npA[blk]];
    const float* c=&full[3*c_npB[blk]];
    float dx=a[0]-c[0], dy=a[1]-c[1], dz=a[2]-c[2];
    float D = sqrtf(dx*dx+dy*dy+dz*dz+1e-6f);
    #pragma unroll
    for (int r=0;r<NRBF;r++){
      float t2 = (D - (20.0f/15.0f)*(float)r)*0.8f;
      vout[blk*16+r] = __expf(-t2*t2);
    }
  }

  float P[6][3];
  for (int o=0;o<6;o++){
    int m = 3*n-1+o;
    if (m>=0 && m<3*NN){
      int res=m/3, at=m-3*res;
      const float* qq = X + ((size_t)b*NN+res)*12 + at*3;
      P[o][0]=qq[0]; P[o][1]=qq[1]; P[o][2]=qq[2];
    } else { P[o][0]=P[o][1]=P[o][2]=0.f; }
  }
  float U[5][3];
  for (int o=0;o<5;o++){
    for(int c=0;c<3;c++) U[o][c]=P[o+1][c]-P[o][c];
    norm3e(U[o]);
  }
  float Dv[3], Av[3];
  for (int r=0;r<3;r++){
    int i3 = 3*n + r;
    if (i3>=1 && i3<=3*NN-3){
      float* u0=U[r]; float* u1=U[r+1]; float* u2=U[r+2];
      float n0[3],n1[3];
      cross3(u0,u1,n0); norm3e(n0);
      cross3(u1,u2,n1); norm3e(n1);
      float cosD = fminf(fmaxf(dot3(n0,n1), -1.f+1e-7f), 1.f-1e-7f);
      float v[3]; cross3(n0,n1,v); norm3e(v);
      float s = -(v[0]*u1[0]+v[1]*u1[1]+v[2]*u1[2]);
      Dv[r] = sgnf(s)*acosf(cosD);
      float cosA = fminf(fmaxf(dot3(u0,u1), -1.f+1e-7f), 1.f-1e-7f);
      Av[r] = acosf(cosA);
    } else { Dv[r]=0.f; Av[r]=0.f; }
  }
  for (int r=0;r<3;r++){
    vout[192+r]=cosf(Dv[r]);
    vout[195+r]=sinf(Dv[r]);
    vout[198+r]=cosf(Av[r]);
    vout[201+r]=sinf(Av[r]);
  }

  const int aord[3]={0,2,3};
  for (int a2=0;a2<3;a2++){
    int a=aord[a2];
    float d[3]; for(int c=0;c<3;c++) d[c]=full[3*a+c]-full[c];
    float dU[3];
    for(int i=0;i<3;i++)
      dU[i]=full[21+3*i]*d[0]+full[21+3*i+1]*d[1]+full[21+3*i+2]*d[2];
    norm3e(dU);
    for(int c=0;c<3;c++) vout[204+3*a2+c]=dU[c];
  }
}

// ---------- shared tail math for edge kernel ----------
__device__ __forceinline__ void edge_tail_quat(const float* own, const float* nbk, float* tl){
  float R[3][3];
  for(int i=0;i<3;i++)for(int l2=0;l2<3;l2++){
    float s=0.f;
    for(int j=0;j<3;j++) s += own[21+3*j+i]*nbk[21+3*j+l2];
    R[i][l2]=s;
  }
  float Rxx=R[0][0],Ryy=R[1][1],Rzz=R[2][2];
  float m0=0.5f*sqrtf(fabsf(1.f+Rxx-Ryy-Rzz));
  float m1=0.5f*sqrtf(fabsf(1.f-Rxx+Ryy-Rzz));
  float m2=0.5f*sqrtf(fabsf(1.f-Rxx-Ryy+Rzz));
  float qx=sgnf(R[2][1]-R[1][2])*m0;
  float qy=sgnf(R[0][2]-R[2][0])*m1;
  float qz=sgnf(R[1][0]-R[0][1])*m2;
  float w =0.5f*sqrtf(fmaxf(1.f+Rxx+Ryy+Rzz,0.f));
  float inv=1.f/fmaxf(sqrtf(qx*qx+qy*qy+qz*qz+w*w),1e-8f);
  tl[0]=qx*inv; tl[1]=qy*inv; tl[2]=qz*inv; tl[3]=w*inv;
}

// ---------- dispatch 2: per-node block, E row (30x480), nontemporal stores ----------
__global__ __launch_bounds__(256) void edge_kernel(const float* __restrict__ packets,
                                                   const float* __restrict__ outIdx,
                                                   float* __restrict__ outE){
  __shared__ __align__(16) float own[32];
  __shared__ __align__(16) float nb[KK][32];
  __shared__ int   jarr[KK];
  __shared__ float dist[KK*29];
  __shared__ __align__(16) float tail[KK][16];

  const int tid = threadIdx.x;
  const int row = blockIdx.x;
  const int b = row/NN;

  if (tid<KK) jarr[tid] = (int)outIdx[(size_t)row*KK+tid];
  if (tid>=248){  // own packet: 8 float4s
    int c = tid-248;
    ((v4f*)own)[c] = ((const v4f*)(packets + (size_t)row*32))[c];
  }
  __syncthreads();

  if (tid < 240){  // neighbor packets: 30 x 8 float4s, coalesced within packet
    int k = tid>>3, c = tid&7;
    ((v4f*)&nb[k][0])[c] =
      ((const v4f*)(packets + ((size_t)b*NN + jarr[k])*32))[c];
  }
  __syncthreads();

  // 870 edge distances
  for (int g=tid; g<KK*29; g+=256){
    int k=g/29, c=g-29*k;
    const float* a  = &own[3*c_epA[c]];
    const float* bq = &nb[k][3*c_epB[c]];
    float dx=a[0]-bq[0], dy=a[1]-bq[1], dz=a[2]-bq[2];
    dist[g] = sqrtf(dx*dx+dy*dy+dz*dz+1e-6f);
  }

  // tail: quats on lanes 0..29, E_direct on threads 64..183 (30x4 items)
  if (tid < KK){
    edge_tail_quat(own, &nb[tid][0], &tail[tid][0]);
  } else if (tid >= 64 && tid < 64+KK*4){
    const int it = tid-64;
    const int k = it>>2, a2 = it&3;
    const int aord[4]={1,0,2,3};   // Ca,N,C,O
    int a=aord[a2];
    float d[3]; for(int c=0;c<3;c++) d[c]=nb[k][3*a+c]-own[c];
    float dU[3];
    for(int i=0;i<3;i++)
      dU[i]=own[21+3*i]*d[0]+own[21+3*i+1]*d[1]+own[21+3*i+2]*d[2];
    norm3e(dU);
    tail[k][4+3*a2+0]=dU[0]; tail[k][4+3*a2+1]=dU[1]; tail[k][4+3*a2+2]=dU[2];
  }
  __syncthreads();

  // float4 nontemporal write of the node's 30x480 E row:
  // per edge 116 RBF-quads + 4 tail-quads (output is write-once, >L2-sized)
  v4f* eb = reinterpret_cast<v4f*>(outE + (size_t)row*KK*E_DIM);
  for (int g=tid; g<KK*120; g+=256){
    int k=g/120, q=g-120*k;
    v4f v;
    if (q < 116){
      float d = dist[k*29 + (q>>2)];
      float r0 = (float)((q&3)*4);
      float t0 = (d - (20.0f/15.0f)*(r0+0.f))*0.8f;
      float t1 = (d - (20.0f/15.0f)*(r0+1.f))*0.8f;
      float t2 = (d - (20.0f/15.0f)*(r0+2.f))*0.8f;
      float t3 = (d - (20.0f/15.0f)*(r0+3.f))*0.8f;
      v.x=__expf(-t0*t0); v.y=__expf(-t1*t1); v.z=__expf(-t2*t2); v.w=__expf(-t3*t3);
    } else {
      const float* tl = &tail[k][(q-116)*4];
      v.x=tl[0]; v.y=tl[1]; v.z=tl[2]; v.w=tl[3];
    }
    __builtin_nontemporal_store(v, &eb[g]);
  }
}

// ---------- launch ----------
extern "C" void kernel_launch(void* const* d_in, const int* in_sizes, int n_in,
                              void* d_out, int out_size, void* d_ws, size_t ws_size,
                              hipStream_t stream) {
  (void)in_sizes; (void)n_in; (void)out_size; (void)ws_size;
  const float* X    = (const float*)d_in[0];
  const float* mask = (const float*)d_in[1];
  const float* vat  = (const float*)d_in[2];
  float* out = (float*)d_out;

  float* outV   = out;
  float* outE   = out + (size_t)NODES*V_DIM;
  float* outIdx = out + (size_t)NODES*V_DIM + (size_t)NODES*KK*E_DIM;
  float* packets = (float*)d_ws;   // NODES*32 floats = 512 KB (ws is ~675 MB)

  hipLaunchKernelGGL(topk_prep_kernel, dim3(NODES + NODES/256), dim3(256), 0, stream,
                     X, mask, vat, outIdx, outV, packets);
  hipLaunchKernelGGL(edge_kernel, dim3(NODES), dim3(256), 0, stream,
                     packets, outIdx, outE);
}

// Round 5
// 280.442 us; speedup vs baseline: 1.0554x; 1.0554x over previous
//
#include <hip/hip_runtime.h>
#include <math.h>

#define BB 2
#define NN 2048
#define KK 30
#define NRBF 16
#define V_DIM 213
#define E_DIM 480
#define NODES (BB*NN)
#define PREPB 64            // prep blocks, launched first
#define NPP 64              // nodes per prep block

typedef unsigned long long u64;
typedef unsigned int u32;
typedef float v4f __attribute__((ext_vector_type(4)));

// ---------- small helpers ----------
__device__ __forceinline__ float sgnf(float x){ return (x>0.f)?1.f:((x<0.f)?-1.f:0.f); }

__device__ __forceinline__ void cross3(const float* a, const float* b, float* c){
  c[0]=a[1]*b[2]-a[2]*b[1];
  c[1]=a[2]*b[0]-a[0]*b[2];
  c[2]=a[0]*b[1]-a[1]*b[0];
}
__device__ __forceinline__ void norm3e(float* v){ // v / max(||v||, 1e-8)
  float n = sqrtf(v[0]*v[0]+v[1]*v[1]+v[2]*v[2]);
  float inv = 1.0f/fmaxf(n,1e-8f);
  v[0]*=inv; v[1]*=inv; v[2]*=inv;
}
__device__ __forceinline__ float dot3(const float* a, const float* b){
  return a[0]*b[0]+a[1]*b[1]+a[2]*b[2];
}

// Given atoms p[12]=N,Ca,C,O of a residue, produce full[30]:
// [0..11]=N,Ca,C,O  [12..14]=Cb  [15..17]=V0  [18..20]=V1  [21..29]=Q rows (b1,n0,b1xn0)
__device__ __forceinline__ void node_derived(const float* p, const float (*va)[3],
                                             float* full, int isLast){
  for(int i=0;i<12;i++) full[i]=p[i];
  float bv[3],cv[3],av[3];
  for(int c=0;c<3;c++){ bv[c]=p[3+c]-p[c]; cv[c]=p[6+c]-p[3+c]; }
  cross3(bv,cv,av);
  for(int c=0;c<3;c++)
    full[12+c] = -0.58273431f*av[c] + 0.56802827f*bv[c] - 0.54067466f*cv[c] + p[3+c];
  for(int i=0;i<2;i++)
    for(int c=0;c<3;c++)
      full[15+3*i+c] = va[i][0]*av[c] + va[i][1]*bv[c] + va[i][2]*cv[c] + p[3+c];
  if (isLast){
    for(int i=0;i<9;i++) full[21+i]=0.f;   // padded Q row for last node
  } else {
    float u0[3],u1[3];
    for(int c=0;c<3;c++){ u0[c]=bv[c]; u1[c]=cv[c]; }
    norm3e(u0); norm3e(u1);
    float n0[3]; cross3(u0,u1,n0); norm3e(n0);
    float b1[3]; for(int c=0;c<3;c++) b1[c]=u0[c]-u1[c];
    norm3e(b1);
    float c2[3]; cross3(b1,n0,c2);
    for(int c=0;c<3;c++){ full[21+c]=b1[c]; full[24+c]=n0[c]; full[27+c]=c2[c]; }
  }
}

// atom indices: N=0,Ca=1,C=2,O=3,Cb=4,V0=5,V1=6
__device__ __constant__ int c_epA[29] = {1,1,2,1,0,4,1,4,0,4,3,4,2,4,1,3,2,2,0,2,3,0,0,3,3, 5,6,6,5};
__device__ __constant__ int c_epB[29] = {1,2,1,0,1,1,4,0,4,3,4,2,4,4,3,1,2,0,2,3,2,0,3,0,3, 5,6,5,6};
__device__ __constant__ int c_npA[12] = {1,1,1,0,0,3,1,4,4,2,6,5};
__device__ __constant__ int c_npB[12] = {0,2,3,2,3,2,4,0,3,4,5,6};

#define NBIN 2048
#define BINSHIFT 21   // bin = float_bits >> 21 (sign0 + exp8 + mant2)

// ---------- fused dispatch 1: prep (first 64 blocks) + topk (next 4096) ----------
__global__ __launch_bounds__(256) void topk_prep_kernel(const float* __restrict__ X,
                                                        const float* __restrict__ mask,
                                                        const float* __restrict__ vatoms,
                                                        float* __restrict__ outIdx,
                                                        float* __restrict__ outV,
                                                        float* __restrict__ packets){
  // manual overlay: topk uses bins(8K)+cand(16K); prep uses pk(8K)+dist(3K)+tail(5.25K)
  __shared__ __align__(16) char smem[24576];
  __shared__ float wred[4];
  __shared__ u32 wsum[4];
  __shared__ int s_cutbin;
  __shared__ u32 s_m;

  const int t = threadIdx.x;

  if (blockIdx.x < PREPB){
    // ================= prep: V features + derived packets, 64 nodes/block =====
    float* pk_s   = (float*)smem;                    // [NPP][32]
    float* dist_s = (float*)(smem + NPP*32*4);       // [NPP][12]
    float* tail_s = (float*)(smem + NPP*32*4 + NPP*12*4); // [NPP][21]
    const int node0 = blockIdx.x * NPP;

    if (t < NPP){
      const int node = node0 + t;
      const int b = node/NN, n = node%NN;

      float va[2][3];
      for(int i=0;i<2;i++){
        float x=vatoms[3*i],y=vatoms[3*i+1],z=vatoms[3*i+2];
        float inv=1.f/sqrtf(x*x+y*y+z*z);
        va[i][0]=x*inv; va[i][1]=y*inv; va[i][2]=z*inv;
      }
      float p[12];
      { const float* q = X + (size_t)node*12; for(int i=0;i<12;i++) p[i]=q[i]; }
      float full[30];
      node_derived(p, va, full, n==NN-1);

      float* pk = pk_s + t*32;
      for (int i=0;i<30;i++) pk[i]=full[i];
      pk[30]=0.f; pk[31]=0.f;

      for (int blk=0; blk<12; blk++){
        const float* a=&full[3*c_npA[blk]];
        const float* c=&full[3*c_npB[blk]];
        float dx=a[0]-c[0], dy=a[1]-c[1], dz=a[2]-c[2];
        dist_s[t*12+blk] = sqrtf(dx*dx+dy*dy+dz*dz+1e-6f);
      }

      float P[6][3];
      for (int o=0;o<6;o++){
        int m = 3*n-1+o;
        if (m>=0 && m<3*NN){
          int res=m/3, at=m-3*res;
          const float* qq = X + ((size_t)b*NN+res)*12 + at*3;
          P[o][0]=qq[0]; P[o][1]=qq[1]; P[o][2]=qq[2];
        } else { P[o][0]=P[o][1]=P[o][2]=0.f; }
      }
      float U[5][3];
      for (int o=0;o<5;o++){
        for(int c=0;c<3;c++) U[o][c]=P[o+1][c]-P[o][c];
        norm3e(U[o]);
      }
      float Dv[3], Av[3];
      for (int r=0;r<3;r++){
        int i3 = 3*n + r;
        if (i3>=1 && i3<=3*NN-3){
          float* u0=U[r]; float* u1=U[r+1]; float* u2=U[r+2];
          float n0[3],n1[3];
          cross3(u0,u1,n0); norm3e(n0);
          cross3(u1,u2,n1); norm3e(n1);
          float cosD = fminf(fmaxf(dot3(n0,n1), -1.f+1e-7f), 1.f-1e-7f);
          float v[3]; cross3(n0,n1,v); norm3e(v);
          float s = -(v[0]*u1[0]+v[1]*u1[1]+v[2]*u1[2]);
          Dv[r] = sgnf(s)*acosf(cosD);
          float cosA = fminf(fmaxf(dot3(u0,u1), -1.f+1e-7f), 1.f-1e-7f);
          Av[r] = acosf(cosA);
        } else { Dv[r]=0.f; Av[r]=0.f; }
      }
      float* tl = tail_s + t*21;
      for (int r=0;r<3;r++){
        tl[0+r]=cosf(Dv[r]);
        tl[3+r]=sinf(Dv[r]);
        tl[6+r]=cosf(Av[r]);
        tl[9+r]=sinf(Av[r]);
      }
      const int aord[3]={0,2,3};
      for (int a2=0;a2<3;a2++){
        int a=aord[a2];
        float d[3]; for(int c=0;c<3;c++) d[c]=full[3*a+c]-full[c];
        float dU[3];
        for(int i=0;i<3;i++)
          dU[i]=full[21+3*i]*d[0]+full[21+3*i+1]*d[1]+full[21+3*i+2]*d[2];
        norm3e(dU);
        for(int c=0;c<3;c++) tl[12+3*a2+c]=dU[c];
      }
    }
    __syncthreads();

    // coalesced V writes: 64 nodes x 213 floats, contiguous across nodes
    float* vbase = outV + (size_t)node0*V_DIM;
    for (int g=t; g<NPP*V_DIM; g+=256){
      int node=g/V_DIM, f=g-V_DIM*node;
      float val;
      if (f < 192){
        float D = dist_s[node*12 + (f>>4)];
        float t2 = (D - (20.0f/15.0f)*(float)(f&15))*0.8f;
        val = __expf(-t2*t2);
      } else {
        val = tail_s[node*21 + (f-192)];
      }
      vbase[g]=val;
    }
    // coalesced packet writes: 64 nodes x 8 float4s, contiguous
    v4f* pdst = (v4f*)(packets + (size_t)node0*32);
    const v4f* psrc = (const v4f*)pk_s;
    for (int g=t; g<NPP*8; g+=256) pdst[g]=psrc[g];
    return;
  }

  // ================= top-k via histogram prune + rank sort =================
  // bins stored transposed: logical bin b at LDS index (b&7)*256 + (b>>3)
  u32* bins = (u32*)smem;                 // 8 KB
  u64* cand = (u64*)(smem + NBIN*4);      // 16 KB

  const int row = blockIdx.x - PREPB;
  const int b = row / NN, n = row % NN;
  const int w = t>>6, l = t&63;

  for (int i=t;i<NBIN;i+=256) bins[i]=0;
  if (t==0) s_m=0;

  const float* Xb = X + (size_t)b*NN*12;
  const float* mb = mask + (size_t)b*NN;
  const float cx=Xb[n*12+3], cy=Xb[n*12+4], cz=Xb[n*12+5], mn=mb[n];

  // distances, bit-exact IEEE (same op order as passing rounds 1-4)
  float dval[8];
  float lmax = -1e30f;
  #pragma unroll
  for (int s=0;s<8;s++){
    int i = s*256+t;
    const float* p = Xb + i*12;
    float dx=__fsub_rn(p[3],cx), dy=__fsub_rn(p[4],cy), dz=__fsub_rn(p[5],cz);
    float ss=__fadd_rn(__fadd_rn(__fadd_rn(__fmul_rn(dx,dx),__fmul_rn(dy,dy)),
                                 __fmul_rn(dz,dz)), 1e-6f);
    float d = __fsqrt_rn(ss);
    float m2 = __fmul_rn(mb[i], mn);
    float om = __fsub_rn(1.0f, m2);
    float D  = __fadd_rn(__fmul_rn(om,10000.0f), __fmul_rn(m2,d));
    dval[s]=D;
    lmax = fmaxf(lmax, D);
  }
  #pragma unroll
  for (int off=32; off; off>>=1) lmax = fmaxf(lmax, __shfl_xor(lmax, off));
  if (l==0) wred[w]=lmax;
  __syncthreads();                       // bins zeroed, wred ready
  const float srmax = fmaxf(fmaxf(wred[0],wred[1]), fmaxf(wred[2],wred[3]));
  const float radd = __fadd_rn(srmax, 1.0f);

  u32 keyb[8];
  #pragma unroll
  for (int s=0;s<8;s++){
    int i = s*256+t;
    float m2 = __fmul_rn(mb[i], mn);
    float om = __fsub_rn(1.0f, m2);
    float Dj = __fadd_rn(dval[s], __fmul_rn(om, radd));
    u32 kb = __float_as_uint(Dj);        // Dj >= 0 -> bits order-isomorphic
    keyb[s]=kb;
    u32 bin = kb >> BINSHIFT;
    atomicAdd(&bins[(bin&7)*256 + (bin>>3)], 1u);
  }
  __syncthreads();

  // scan: thread t owns logical bins [8t, 8t+8)
  u32 g8[8]; u32 lsum=0;
  #pragma unroll
  for (int j=0;j<8;j++){ g8[j]=bins[j*256+t]; lsum+=g8[j]; }
  u32 inc=lsum;
  #pragma unroll
  for (int off=1; off<64; off<<=1){
    u32 o = __shfl_up(inc, off);
    if (l >= off) inc += o;
  }
  if (l==63) wsum[w]=inc;
  __syncthreads();
  u32 waveoff=0;
  for (int ww=0; ww<w; ww++) waveoff += wsum[ww];
  u32 run = waveoff + inc - lsum;        // exclusive prefix of this 8-bin group
  #pragma unroll
  for (int j=0;j<8;j++){
    u32 c=g8[j];
    if (run < KK && run + c >= KK) s_cutbin = 8*t+j;   // unique writer
    run += c;
  }
  __syncthreads();
  const int cutbin = s_cutbin;

  // collect candidates (all bins <= cutbin); >=30 guaranteed
  #pragma unroll
  for (int s=0;s<8;s++){
    if ((int)(keyb[s] >> BINSHIFT) <= cutbin){
      u32 slot = atomicAdd(&s_m, 1u);
      cand[slot] = ((u64)keyb[s] << 32) | (u32)(s*256+t);
    }
  }
  __syncthreads();
  const int m = (int)s_m;

  // exact rank (keys unique: idx in low bits) -> scatter; order == lax.top_k
  for (int cix=t; cix<m; cix+=256){
    u64 mykey = cand[cix];
    int rank=0;
    for (int j=0;j<m;j++) rank += (cand[j] < mykey) ? 1 : 0;
    if (rank < KK)
      outIdx[(size_t)row*KK + rank] = (float)(u32)(mykey & 0xffffffffu);
  }
}

// ---------- shared tail math for edge kernel ----------
__device__ __forceinline__ void edge_tail_quat(const float* own, const float* nbk, float* tl){
  float R[3][3];
  for(int i=0;i<3;i++)for(int l2=0;l2<3;l2++){
    float s=0.f;
    for(int j=0;j<3;j++) s += own[21+3*j+i]*nbk[21+3*j+l2];
    R[i][l2]=s;
  }
  float Rxx=R[0][0],Ryy=R[1][1],Rzz=R[2][2];
  float m0=0.5f*sqrtf(fabsf(1.f+Rxx-Ryy-Rzz));
  float m1=0.5f*sqrtf(fabsf(1.f-Rxx+Ryy-Rzz));
  float m2=0.5f*sqrtf(fabsf(1.f-Rxx-Ryy+Rzz));
  float qx=sgnf(R[2][1]-R[1][2])*m0;
  float qy=sgnf(R[0][2]-R[2][0])*m1;
  float qz=sgnf(R[1][0]-R[0][1])*m2;
  float w =0.5f*sqrtf(fmaxf(1.f+Rxx+Ryy+Rzz,0.f));
  float inv=1.f/fmaxf(sqrtf(qx*qx+qy*qy+qz*qz+w*w),1e-8f);
  tl[0]=qx*inv; tl[1]=qy*inv; tl[2]=qz*inv; tl[3]=w*inv;
}

// ---------- dispatch 2: per-node block, E row (30x480), nontemporal stores ----------
__global__ __launch_bounds__(256) void edge_kernel(const float* __restrict__ packets,
                                                   const float* __restrict__ outIdx,
                                                   float* __restrict__ outE){
  __shared__ __align__(16) float own[32];
  __shared__ __align__(16) float nb[KK][32];
  __shared__ int   jarr[KK];
  __shared__ float dist[KK*29];
  __shared__ __align__(16) float tail[KK][16];

  const int tid = threadIdx.x;
  const int row = blockIdx.x;
  const int b = row/NN;

  if (tid<KK) jarr[tid] = (int)outIdx[(size_t)row*KK+tid];
  if (tid>=248){  // own packet: 8 float4s
    int c = tid-248;
    ((v4f*)own)[c] = ((const v4f*)(packets + (size_t)row*32))[c];
  }
  __syncthreads();

  if (tid < 240){  // neighbor packets: 30 x 8 float4s, coalesced within packet
    int k = tid>>3, c = tid&7;
    ((v4f*)&nb[k][0])[c] =
      ((const v4f*)(packets + ((size_t)b*NN + jarr[k])*32))[c];
  }
  __syncthreads();

  // 870 edge distances
  for (int g=tid; g<KK*29; g+=256){
    int k=g/29, c=g-29*k;
    const float* a  = &own[3*c_epA[c]];
    const float* bq = &nb[k][3*c_epB[c]];
    float dx=a[0]-bq[0], dy=a[1]-bq[1], dz=a[2]-bq[2];
    dist[g] = sqrtf(dx*dx+dy*dy+dz*dz+1e-6f);
  }

  // tail: quats on lanes 0..29, E_direct on threads 64..183 (30x4 items)
  if (tid < KK){
    edge_tail_quat(own, &nb[tid][0], &tail[tid][0]);
  } else if (tid >= 64 && tid < 64+KK*4){
    const int it = tid-64;
    const int k = it>>2, a2 = it&3;
    const int aord[4]={1,0,2,3};   // Ca,N,C,O
    int a=aord[a2];
    float d[3]; for(int c=0;c<3;c++) d[c]=nb[k][3*a+c]-own[c];
    float dU[3];
    for(int i=0;i<3;i++)
      dU[i]=own[21+3*i]*d[0]+own[21+3*i+1]*d[1]+own[21+3*i+2]*d[2];
    norm3e(dU);
    tail[k][4+3*a2+0]=dU[0]; tail[k][4+3*a2+1]=dU[1]; tail[k][4+3*a2+2]=dU[2];
  }
  __syncthreads();

  // float4 nontemporal write of the node's 30x480 E row:
  // per edge 116 RBF-quads + 4 tail-quads (output is write-once, >L2-sized)
  v4f* eb = reinterpret_cast<v4f*>(outE + (size_t)row*KK*E_DIM);
  for (int g=tid; g<KK*120; g+=256){
    int k=g/120, q=g-120*k;
    v4f v;
    if (q < 116){
      float d = dist[k*29 + (q>>2)];
      float r0 = (float)((q&3)*4);
      float t0 = (d - (20.0f/15.0f)*(r0+0.f))*0.8f;
      float t1 = (d - (20.0f/15.0f)*(r0+1.f))*0.8f;
      float t2 = (d - (20.0f/15.0f)*(r0+2.f))*0.8f;
      float t3 = (d - (20.0f/15.0f)*(r0+3.f))*0.8f;
      v.x=__expf(-t0*t0); v.y=__expf(-t1*t1); v.z=__expf(-t2*t2); v.w=__expf(-t3*t3);
    } else {
      const float* tl = &tail[k][(q-116)*4];
      v.x=tl[0]; v.y=tl[1]; v.z=tl[2]; v.w=tl[3];
    }
    __builtin_nontemporal_store(v, &eb[g]);
  }
}

// ---------- launch ----------
extern "C" void kernel_launch(void* const* d_in, const int* in_sizes, int n_in,
                              void* d_out, int out_size, void* d_ws, size_t ws_size,
                              hipStream_t stream) {
  (void)in_sizes; (void)n_in; (void)out_size; (void)ws_size;
  const float* X    = (const float*)d_in[0];
  const float* mask = (const float*)d_in[1];
  const float* vat  = (const float*)d_in[2];
  float* out = (float*)d_out;

  float* outV   = out;
  float* outE   = out + (size_t)NODES*V_DIM;
  float* outIdx = out + (size_t)NODES*V_DIM + (size_t)NODES*KK*E_DIM;
  float* packets = (float*)d_ws;   // NODES*32 floats = 512 KB

  hipLaunchKernelGGL(topk_prep_kernel, dim3(PREPB + NODES), dim3(256), 0, stream,
                     X, mask, vat, outIdx, outV, packets);
  hipLaunchKernelGGL(edge_kernel, dim3(NODES), dim3(256), 0, stream,
                     packets, outIdx, outE);
}